// Round 8
// baseline (1461.109 us; speedup 1.0000x reference)
//
#include <hip/hip_runtime.h>
#include <cfloat>
#include <cmath>

// FPS: B=4, N=8192, S=1024. One block/batch; points + running min-distance
// (SQUARED space) in registers (8 pts/thread x 1024 thr). LDS: float4 cloud
// copy (coord broadcast, 1x ds_read_b128) + 16 double-buffered uint2 slots.
//
// One barrier per iteration, no atomics:
//  pre-barrier (wave-parallel): thread tie-candidate scan (bitwise ==, with a
//    conservative 1e-6 margin filter; exact sqrt scan only on rare near-ties
//    -- any true sqrt collision is within 2.4e-7 relative, margin covers 4x),
//    then paired (sU_bits, idx) 6-step DPP wave reduce -> lane63 writes uint2.
//  barrier.
//  post-barrier: all lanes read slot[lane&15] (LDS broadcast), 4-step
//    row_ror 8/4/2/1 paired DPP reduce -> ALL lanes hold (block max sqrt,
//    min tie index). No post-barrier sqrt, no second barrier.
//
// Exactness (validated bit-exact rounds 4/5): round(sqrt) monotone => min/max
// commute; ties compared on sqrtf values exactly as the reference compares ds;
// min-index merge == jnp.argmax first-occurrence. Degenerate all-zero-distance
// clouds (sU==0 colliding with DPP bound_ctrl zero-fill) cannot occur with
// this input distribution.
//
// Slot race audit: iter s writes slot[s&1] pre-barrier(s), reads post-barrier(s);
// next write of slot[s&1] is iter s+2 pre-barrier(s+2); the read and that write
// are separated by barrier(s+1) in both threads' program order => safe.

#define NPTS 8192
#define NSAMP 1024
#define TPB 1024
#define PPT (NPTS / TPB)   // 8 points per thread
#define NW (TPB / 64)      // 16 waves

// Paired (value ps, index pi) DPP merge: max on ps (uint order == float order
// for nonneg), min on pi at equal ps. Compiler-visible DPP (hazards handled).
#define PAIR_MERGE(CTRL)                                                              \
    do {                                                                              \
        const unsigned ts = (unsigned)__builtin_amdgcn_update_dpp(0, (int)ps, (CTRL), 0xF, 0xF, true); \
        const unsigned ti = (unsigned)__builtin_amdgcn_update_dpp(0, (int)pi, (CTRL), 0xF, 0xF, true); \
        const bool take = (ts > ps) | ((ts == ps) & (ti < pi));                       \
        ps = take ? ts : ps;                                                          \
        pi = take ? ti : pi;                                                          \
    } while (0)

__global__ __launch_bounds__(TPB) void fps_kernel(const float* __restrict__ pts,
                                                  float* __restrict__ out) {
#pragma clang fp contract(off)
    const int b = blockIdx.x;
    const int tid = threadIdx.x;
    const float* __restrict__ P = pts + (size_t)b * NPTS * 3;
    float* __restrict__ O = out + (size_t)b * NSAMP * 3;

    __shared__ float4 sp4[NPTS];        // 128 KB cloud copy (x,y,z,0)
    __shared__ uint2  sSlot[2][NW];     // per-wave (sU_bits, candIdx), dbuf

    float px[PPT], py[PPT], pz[PPT], dsq[PPT];

    const float p0x = P[0], p0y = P[1], p0z = P[2];

    // Load -> regs + LDS; dsq = ||p-p0||^2 (ref op order, contraction OFF).
    float tmax = 0.0f;
#pragma unroll
    for (int j = 0; j < PPT; ++j) {
        const int i = j * TPB + tid;          // stride-TPB point ownership
        const float x = P[i * 3 + 0];
        const float y = P[i * 3 + 1];
        const float z = P[i * 3 + 2];
        px[j] = x; py[j] = y; pz[j] = z;
        sp4[i] = make_float4(x, y, z, 0.0f);
        const float dx = x - p0x, dy = y - p0y, dz = z - p0z;
        const float sq = (dx * dx + dy * dy) + dz * dz;
        dsq[j] = sq;
        tmax = fmaxf(tmax, sq);
    }
    __syncthreads();

    const int lane = tid & 63;
    const int wid  = tid >> 6;

    for (int s = 0; s < NSAMP; ++s) {
        const int buf = s & 1;

        // ---- thread tie-candidate (pre-barrier, cheap path bitwise) ----
        unsigned cj = 0u;
        bool near_tie = false;
        const float thresh = tmax * 0.999999f;   // covers any sqrt collision (4x slack)
#pragma unroll
        for (int j = PPT - 1; j >= 0; --j) {
            near_tie |= (dsq[j] >= thresh) & (dsq[j] != tmax);
            if (dsq[j] == tmax) cj = (unsigned)j;     // descending: ends at min j
        }
        const float sU = sqrtf(tmax);            // thread's max in sqrt space
        if (near_tie) {                          // rare exact path
#pragma unroll
            for (int j = PPT - 1; j >= 0; --j)
                if (dsq[j] >= thresh && sqrtf(dsq[j]) == sU) cj = (unsigned)j;
        }

        // ---- paired 64-lane DPP reduce: (max sU, min idx on tie) -> lane63 ----
        unsigned ps = __float_as_uint(sU);
        unsigned pi = cj * TPB + (unsigned)tid;
        PAIR_MERGE(0x111);   // row_shr:1
        PAIR_MERGE(0x112);   // row_shr:2
        PAIR_MERGE(0x114);   // row_shr:4
        PAIR_MERGE(0x118);   // row_shr:8
        PAIR_MERGE(0x142);   // row_bcast:15
        PAIR_MERGE(0x143);   // row_bcast:31
        if (lane == 63) sSlot[buf][wid] = make_uint2(ps, pi);
        __syncthreads();                          // the ONE barrier

        // ---- combine NW=16 wave slots: all lanes, 4-step row_ror reduce ----
        const uint2 pr = sSlot[buf][lane & (NW - 1)];   // broadcast-read
        ps = pr.x; pi = pr.y;
        PAIR_MERGE(0x128);   // row_ror:8
        PAIR_MERGE(0x124);   // row_ror:4
        PAIR_MERGE(0x122);   // row_ror:2
        PAIR_MERGE(0x121);   // row_ror:1  -> every lane: block (max, argmin-tie)

        const int gidx = (int)pi;                 // uniform across block
        const float4 c = sp4[gidx];               // single ds_read_b128 broadcast
        const float sx = c.x, sy = c.y, sz = c.z;

        if (tid == 0) {
            O[s * 3 + 0] = sx;
            O[s * 3 + 1] = sy;
            O[s * 3 + 2] = sz;
        }

        // ---- min-update in squared space: 10 VALU/pt, no sqrt ----
        tmax = 0.0f;
#pragma unroll
        for (int j = 0; j < PPT; ++j) {
            const float dx = px[j] - sx;
            const float dy = py[j] - sy;
            const float dz = pz[j] - sz;
            const float nd = (dx * dx + dy * dy) + dz * dz;   // contraction OFF
            const float d  = fminf(dsq[j], nd);
            dsq[j] = d;
            tmax = fmaxf(tmax, d);
        }
    }
}

extern "C" void kernel_launch(void* const* d_in, const int* in_sizes, int n_in,
                              void* d_out, int out_size, void* d_ws, size_t ws_size,
                              hipStream_t stream) {
    const float* pts = (const float*)d_in[0];
    float* out = (float*)d_out;
    const int B = in_sizes[0] / (NPTS * 3);   // 4
    fps_kernel<<<B, TPB, 0, stream>>>(pts, out);
}

// Round 13
// 1220.286 us; speedup vs baseline: 1.1973x; 1.1973x over previous
//
#include <hip/hip_runtime.h>
#include <cfloat>
#include <cmath>

// FPS: B=4, N=8192, S=1024. One block/batch; SQUARED-space min-distances in
// registers, 16 pts/thread x 512 threads (8 waves = 2/SIMD). LDS: float4
// cloud (coord broadcast) + 8 double-buffered uint2 key slots.
//
// R8 post-mortem: kernel is VALU-ISSUE-bound (~89% per-CU VALUBusy); overhead
// (reduce/scan/sqrt ~250 instr) is per-THREAD while update is per-POINT.
// => halve threads (512, PPT=16): per-SIMD overhead issue halves, update
// issue constant. Also: u64-key merge (5-6 instr/step vs 9-10) and argmax +
// second-max folded into the update loop (near-tie scan -> 1 post compare).
//
// Exactness (bit-exact R5/R8): round(sqrt) monotone => min/max commute with
// sqrt; block winner = max over per-thread keys (sqrtf(tmax)_bits<<32 | ~gidx)
// => max sqrt value, min global index on sqrt-ties == jnp.argmax first-
// occurrence. Within-thread: in-loop strict-> argmax = first occurrence of
// max dsq; rare sqrt-collision (distinct dsq, equal sqrt, detected by
// m2 >= mval*(1-1e-6), 4x wider than the 2.4e-7 max collision gap) takes an
// exec-masked exact descending sqrt scan. bound_ctrl zero-fill key (0,0)
// loses to any nonzero-distance key; all-zero clouds impossible here.
//
// Slot race: write slot[s&1] pre-barrier(s), read post-barrier(s); next write
// is pre-barrier(s+2), separated from the read by barrier(s+1). Safe.

#define NPTS 8192
#define NSAMP 1024
#define TPB 512
#define PPT (NPTS / TPB)   // 16 points per thread
#define NW (TPB / 64)      // 8 waves

// u64-key DPP merge: key = (value_bits << 32) | ~index. max-key == (max value,
// then min index). Two compiler-visible DPP movs + u64 compare + 2 selects.
#define KEY_MERGE(CTRL)                                                               \
    do {                                                                              \
        const unsigned th = (unsigned)__builtin_amdgcn_update_dpp(0, (int)kh, (CTRL), 0xF, 0xF, true); \
        const unsigned tl = (unsigned)__builtin_amdgcn_update_dpp(0, (int)kl, (CTRL), 0xF, 0xF, true); \
        const unsigned long long tk = ((unsigned long long)th << 32) | tl;            \
        const unsigned long long pk = ((unsigned long long)kh << 32) | kl;            \
        const bool take = tk > pk;                                                    \
        kh = take ? th : kh;                                                          \
        kl = take ? tl : kl;                                                          \
    } while (0)

__global__ __launch_bounds__(TPB) void fps_kernel(const float* __restrict__ pts,
                                                  float* __restrict__ out) {
#pragma clang fp contract(off)
    const int b = blockIdx.x;
    const int tid = threadIdx.x;
    const float* __restrict__ P = pts + (size_t)b * NPTS * 3;
    float* __restrict__ O = out + (size_t)b * NSAMP * 3;

    __shared__ float4 sp4[NPTS];        // 128 KB cloud copy (x,y,z,0)
    __shared__ uint2  sSlot[2][NW];     // per-wave (kl=~idx, kh=sqrt_bits), dbuf

    float px[PPT], py[PPT], pz[PPT], dsq[PPT];

    const float p0x = P[0], p0y = P[1], p0z = P[2];

    // Load -> regs + LDS; dsq = ||p-p0||^2 (ref op order, contraction OFF).
    // Track (mval, mj) argmax first-occurrence + m2 second-max in-loop.
    float mval = -FLT_MAX, m2 = -FLT_MAX;
    int mj = 0;
#pragma unroll
    for (int j = 0; j < PPT; ++j) {
        const int i = j * TPB + tid;          // stride-TPB point ownership
        const float x = P[i * 3 + 0];
        const float y = P[i * 3 + 1];
        const float z = P[i * 3 + 2];
        px[j] = x; py[j] = y; pz[j] = z;
        sp4[i] = make_float4(x, y, z, 0.0f);
        const float dx = x - p0x, dy = y - p0y, dz = z - p0z;
        const float d = (dx * dx + dy * dy) + dz * dz;
        dsq[j] = d;
        const float t = fminf(d, mval);       // loser of (d, old max)
        m2 = fmaxf(m2, t);
        if (d > mval) { mval = d; mj = j; }   // strict >: first occurrence
    }
    __syncthreads();

    const int lane = tid & 63;
    const int wid  = tid >> 6;

    for (int s = 0; s < NSAMP; ++s) {
        const int buf = s & 1;

        // ---- per-thread winner in sqrt space ----
        const float sU = sqrtf(mval);
        if (m2 >= mval * 0.999999f) {         // rare: possible sqrt collision
#pragma unroll
            for (int j = PPT - 1; j >= 0; --j)
                if (sqrtf(dsq[j]) == sU) mj = j;   // descending -> min j
        }
        unsigned kh = __float_as_uint(sU);
        unsigned kl = ~(unsigned)(mj * TPB + tid);

        // ---- 64-lane key reduce -> lane 63 ----
        KEY_MERGE(0x111);   // row_shr:1
        KEY_MERGE(0x112);   // row_shr:2
        KEY_MERGE(0x114);   // row_shr:4
        KEY_MERGE(0x118);   // row_shr:8
        KEY_MERGE(0x142);   // row_bcast:15
        KEY_MERGE(0x143);   // row_bcast:31
        if (lane == 63) sSlot[buf][wid] = make_uint2(kl, kh);
        __syncthreads();                      // the ONE barrier

        // ---- combine NW=8 wave slots: row_ror 4/2/1 covers all 8 ----
        const uint2 pr = sSlot[buf][lane & (NW - 1)];
        kl = pr.x; kh = pr.y;
        KEY_MERGE(0x124);   // row_ror:4
        KEY_MERGE(0x122);   // row_ror:2
        KEY_MERGE(0x121);   // row_ror:1  -> all lanes: block winner key

        const int gidx = (int)(~kl);          // uniform across block
        const float4 c = sp4[gidx];           // single ds_read_b128 broadcast
        const float sx = c.x, sy = c.y, sz = c.z;

        if (tid == 0) {
            O[s * 3 + 0] = sx;
            O[s * 3 + 1] = sy;
            O[s * 3 + 2] = sz;
        }

        // ---- min-update + argmax/second-max tracking (14 VALU/pt) ----
        mval = -FLT_MAX; m2 = -FLT_MAX; mj = 0;
#pragma unroll
        for (int j = 0; j < PPT; ++j) {
            const float dx = px[j] - sx;
            const float dy = py[j] - sy;
            const float dz = pz[j] - sz;
            const float nd = (dx * dx + dy * dy) + dz * dz;   // contraction OFF
            const float d  = fminf(dsq[j], nd);
            dsq[j] = d;
            const float t = fminf(d, mval);
            m2 = fmaxf(m2, t);
            if (d > mval) { mval = d; mj = j; }
        }
    }
}

extern "C" void kernel_launch(void* const* d_in, const int* in_sizes, int n_in,
                              void* d_out, int out_size, void* d_ws, size_t ws_size,
                              hipStream_t stream) {
    const float* pts = (const float*)d_in[0];
    float* out = (float*)d_out;
    const int B = in_sizes[0] / (NPTS * 3);   // 4
    fps_kernel<<<B, TPB, 0, stream>>>(pts, out);
}

// Round 14
// 1147.384 us; speedup vs baseline: 1.2734x; 1.0635x over previous
//
#include <hip/hip_runtime.h>
#include <cfloat>
#include <cmath>

// FPS: B=4, N=8192, S=1024. One block/batch; SQUARED-space min-distances in
// registers, 32 pts/thread x 256 threads (4 waves = 1/SIMD, exclusive).
// LDS: float4 cloud (coord broadcast) + 12KB output buffer + 4 key slots.
//
// R13 post-mortem: halving threads gave -17% (confirmed per-thread overhead
// theory) but exposed ~1600 cyc/iter of SERIAL latency. R14 levers:
//  (1) O[] stores -> LDS buffer + epilogue copy: __syncthreads emits
//      s_waitcnt vmcnt(0); an in-loop global store makes wave 0 drain it
//      every iteration on the barrier path.
//  (2) TPB=256/PPT=32: overhead issue halves again; update issue constant.
//  (3) post-barrier: 4 slots fit 32B -> all lanes read 2x uint4 (b128) and
//      redundantly tree-reduce 4 u64 keys in registers (no DPP, no ror
//      chain, no second LDS round-trip for slot combine).
//
// Exactness (bit-exact R5/R8/R13): round(sqrt) monotone => min/max commute
// with sqrt; block winner = max over per-thread keys (sqrt_bits<<32 | ~gidx)
// => max sqrt value, min global index on sqrt-ties == jnp.argmax first-
// occurrence. Within-thread: strict-> argmax = first occurrence; rare
// sqrt-collision (second-max m2 >= mval*(1-1e-6), 4x wider than the 2.4e-7
// max collision gap) takes an exec-masked exact descending sqrt scan.
// bound_ctrl zero-fill key (0,0) loses to any nonzero-distance key.
//
// Slot race: write sSlot[s&1] pre-barrier(s), read post-barrier(s); next
// write pre-barrier(s+2), separated from the read by barrier(s+1). Safe.

#define NPTS 8192
#define NSAMP 1024
#define TPB 256
#define PPT (NPTS / TPB)   // 32 points per thread
#define NW (TPB / 64)      // 4 waves

// u64-key DPP merge (pre-barrier wave reduce): key = (value_bits<<32) | ~idx.
#define KEY_MERGE(CTRL)                                                               \
    do {                                                                              \
        const unsigned th = (unsigned)__builtin_amdgcn_update_dpp(0, (int)kh, (CTRL), 0xF, 0xF, true); \
        const unsigned tl = (unsigned)__builtin_amdgcn_update_dpp(0, (int)kl, (CTRL), 0xF, 0xF, true); \
        const unsigned long long tk = ((unsigned long long)th << 32) | tl;            \
        const unsigned long long pk = ((unsigned long long)kh << 32) | kl;            \
        const bool take = tk > pk;                                                    \
        kh = take ? th : kh;                                                          \
        kl = take ? tl : kl;                                                          \
    } while (0)

__global__ __launch_bounds__(TPB) void fps_kernel(const float* __restrict__ pts,
                                                  float* __restrict__ out) {
#pragma clang fp contract(off)
    const int b = blockIdx.x;
    const int tid = threadIdx.x;
    const float* __restrict__ P = pts + (size_t)b * NPTS * 3;
    float* __restrict__ O = out + (size_t)b * NSAMP * 3;

    __shared__ float4 sp4[NPTS];                    // 128 KB cloud copy
    __shared__ float  sOut[NSAMP * 3];              // 12 KB selected coords
    __shared__ __align__(16) uint2 sSlot[2][NW];    // 4 key slots, dbuf

    float px[PPT], py[PPT], pz[PPT], dsq[PPT];

    const float p0x = P[0], p0y = P[1], p0z = P[2];

    // Load -> regs + LDS; dsq = ||p-p0||^2 (ref op order, contraction OFF).
    // Track (mval, mj) argmax first-occurrence + m2 second-max in-loop.
    float mval = -FLT_MAX, m2 = -FLT_MAX;
    int mj = 0;
#pragma unroll
    for (int j = 0; j < PPT; ++j) {
        const int i = j * TPB + tid;          // stride-TPB point ownership
        const float x = P[i * 3 + 0];
        const float y = P[i * 3 + 1];
        const float z = P[i * 3 + 2];
        px[j] = x; py[j] = y; pz[j] = z;
        sp4[i] = make_float4(x, y, z, 0.0f);
        const float dx = x - p0x, dy = y - p0y, dz = z - p0z;
        const float d = (dx * dx + dy * dy) + dz * dz;
        dsq[j] = d;
        const float t = fminf(d, mval);       // loser of (d, old max)
        m2 = fmaxf(m2, t);
        if (d > mval) { mval = d; mj = j; }   // strict >: first occurrence
    }
    __syncthreads();

    const int lane = tid & 63;
    const int wid  = tid >> 6;

    for (int s = 0; s < NSAMP; ++s) {
        const int buf = s & 1;

        // ---- per-thread winner in sqrt space ----
        const float sU = sqrtf(mval);
        if (m2 >= mval * 0.999999f) {         // rare: possible sqrt collision
#pragma unroll
            for (int j = PPT - 1; j >= 0; --j)
                if (sqrtf(dsq[j]) == sU) mj = j;   // descending -> min j
        }
        unsigned kh = __float_as_uint(sU);
        unsigned kl = ~(unsigned)(mj * TPB + tid);

        // ---- 64-lane key reduce -> lane 63 (6 DPP merges) ----
        KEY_MERGE(0x111);   // row_shr:1
        KEY_MERGE(0x112);   // row_shr:2
        KEY_MERGE(0x114);   // row_shr:4
        KEY_MERGE(0x118);   // row_shr:8
        KEY_MERGE(0x142);   // row_bcast:15
        KEY_MERGE(0x143);   // row_bcast:31
        if (lane == 63) sSlot[buf][wid] = make_uint2(kl, kh);
        __syncthreads();                      // the ONE barrier

        // ---- all lanes read all 4 slots (2x b128), register u64 tree ----
        const uint4* sl = reinterpret_cast<const uint4*>(&sSlot[buf][0]);
        const uint4 a = sl[0];                // slots 0,1: (kl0,kh0,kl1,kh1)
        const uint4 c4 = sl[1];               // slots 2,3
        const unsigned long long K0 = ((unsigned long long)a.y  << 32) | a.x;
        const unsigned long long K1 = ((unsigned long long)a.w  << 32) | a.z;
        const unsigned long long K2 = ((unsigned long long)c4.y << 32) | c4.x;
        const unsigned long long K3 = ((unsigned long long)c4.w << 32) | c4.z;
        const unsigned long long m01 = K0 > K1 ? K0 : K1;
        const unsigned long long m23 = K2 > K3 ? K2 : K3;
        const unsigned long long K   = m01 > m23 ? m01 : m23;

        const int gidx = (int)(~(unsigned)K); // uniform across block
        const float4 c = sp4[gidx];           // single ds_read_b128 broadcast
        const float sx = c.x, sy = c.y, sz = c.z;

        if (tid == 0) {                       // LDS, not global: no vmcnt drain
            sOut[s * 3 + 0] = sx;
            sOut[s * 3 + 1] = sy;
            sOut[s * 3 + 2] = sz;
        }

        // ---- min-update + argmax/second-max tracking (14 VALU/pt) ----
        mval = -FLT_MAX; m2 = -FLT_MAX; mj = 0;
#pragma unroll
        for (int j = 0; j < PPT; ++j) {
            const float dx = px[j] - sx;
            const float dy = py[j] - sy;
            const float dz = pz[j] - sz;
            const float nd = (dx * dx + dy * dy) + dz * dz;   // contraction OFF
            const float d  = fminf(dsq[j], nd);
            dsq[j] = d;
            const float t = fminf(d, mval);
            m2 = fmaxf(m2, t);
            if (d > mval) { mval = d; mj = j; }
        }
    }

    // ---- epilogue: one coalesced copy LDS -> global ----
    __syncthreads();
#pragma unroll
    for (int k = tid; k < NSAMP * 3; k += TPB)
        O[k] = sOut[k];
}

extern "C" void kernel_launch(void* const* d_in, const int* in_sizes, int n_in,
                              void* d_out, int out_size, void* d_ws, size_t ws_size,
                              hipStream_t stream) {
    const float* pts = (const float*)d_in[0];
    float* out = (float*)d_out;
    const int B = in_sizes[0] / (NPTS * 3);   // 4
    fps_kernel<<<B, TPB, 0, stream>>>(pts, out);
}